// Round 6
// baseline (1309.660 us; speedup 1.0000x reference)
//
#include <hip/hip_runtime.h>

// Signature-kernel MMD via Goursat PDE — round 7b (resubmit; round-7 bench
// died in container acquire, no kernel verdict — source audited for OOB /
// capture violations, none found).
// Round-6 postmortem: running-dot identity re-spilled (WRITE 39MB) — extra
// live state (Es/Et, prologue row) over the 32 pinned floats at cap 64.
// Also: total-minus-pde is ~42us HARNESS overhead independent of kernel
// count (r6 single-kernel proved it) -> sig_diff costs ~nothing. And
// OccupancyPercent reads 48% in every config (derived-formula artifact,
// not half-residency): rounds 3-5 occupancy theory was wrong.
// Remaining 30% non-issue gap attributed to depth-1 s_load prefetch: each
// dX row's s_load_dwordx16 is issued ~95cy before its lgkmcnt wait vs
// 100-300cy scalar-cache latency -> every wave stalls every row.
// Round-7 (proven r2/r4 structure + three fixes):
//  (1) depth-4 ring prefetch: 4 rows of named float4 SGPR quads, unroll-4,
//      loads issued ~380cy ahead. dInc pitch 2048 (128 rows) pads the ring.
//  (2) float4-direct SIG_ROW operands (no float[] unpack movs; ~46
//      VALU/row static vs ~70 measured before); fold +1 via T=S+1.
//  (3) 2112 straight blocks (r2 grid, measured 6us better than dual-task),
//      no outer task loop; pins + block-uniform decode + atomic reduce.

#define XY_BLOCKS 1024
#define TRI_BLOCKS 544
#define NBT (XY_BLOCKS + 2 * TRI_BLOCKS)        // 2112 blocks
#define MAT4 32768                              // float4 per matrix (64 paths)

template <int C, int RM, int BM, bool BC>
__device__ __forceinline__ float dpp0(float x) {
    return __builtin_bit_cast(float, __builtin_amdgcn_update_dpp(
        0, __builtin_bit_cast(int, x), C, RM, BM, BC));
}

// 64-lane inclusive prefix sum, pure VALU (6 dependent adds).
__device__ __forceinline__ float wave_scan_incl(float v) {
    v += dpp0<0x111, 0xf, 0xf, true>(v);   // row_shr:1
    v += dpp0<0x112, 0xf, 0xf, true>(v);   // row_shr:2
    v += dpp0<0x114, 0xf, 0xf, true>(v);   // row_shr:4
    v += dpp0<0x118, 0xf, 0xf, true>(v);   // row_shr:8
    v += dpp0<0x142, 0xa, 0xf, false>(v);  // row_bcast:15 -> rows 1,3
    v += dpp0<0x143, 0xc, 0xf, false>(v);  // row_bcast:31 -> rows 2,3
    return v;
}

// lane l gets lane l-1's x; lane 0 gets `oldv`.
__device__ __forceinline__ float wave_shr1(float x, float oldv) {
    return __builtin_bit_cast(float, __builtin_amdgcn_update_dpp(
        __builtin_bit_cast(int, oldv), __builtin_bit_cast(int, x),
        0x138, 0xf, 0xf, false));          // wave_shr:1
}

// ---- kernel 1: path increments X,Y -> ws, pitch 2048 floats per path ----
// (row 127 of each path left unwritten — ring prefetch pad, never consumed)
// Also zeroes out[0] for the fused atomic reduction in sig_pde7.
__global__ __launch_bounds__(256) void sig_diff(
    const float* __restrict__ X, const float* __restrict__ Y,
    float* __restrict__ dInc, float* __restrict__ out)
{
    if (blockIdx.x == 0 && threadIdx.x == 0) out[0] = 0.0f;
    int i = blockIdx.x * 256 + threadIdx.x;   // work id, 65024 total
    if (i >= 65024) return;
    int which = (i >= 32512) ? 1 : 0;
    int j = i - which * 32512;
    int a = j / 508;                          // 127*4 float4 per path
    int rq = j - a * 508;                     // r*4 + q
    const float* S = which ? Y : X;
    const float4* p = (const float4*)S + a * 512 + rq;
    float4 v0 = p[0], v1 = p[4];              // +16 floats = next row
    float4 d;
    d.x = v1.x - v0.x; d.y = v1.y - v0.y;
    d.z = v1.z - v0.z; d.w = v1.w - v0.w;
    ((float4*)dInc)[which * MAT4 + a * 512 + rq] = d;
}

// ---- kernel 2: PDE. 2112 blocks * 4 waves, one (g,a,b0) per block. ----
__global__ __launch_bounds__(256, 8) void sig_pde7(
    const float* __restrict__ dInc, float* __restrict__ out)
{
    __shared__ float red[4];
    const int wid  = threadIdx.x >> 6;
    const int lane = threadIdx.x & 63;
    const int BT   = blockIdx.x;

    // block-uniform decode -> (gram g, a, b0); b = b0 + wave id
    int g, a, b0;
    if (BT < XY_BLOCKS) {                  // XY: dense 64x64
        g = 2; a = BT >> 4; b0 = (BT & 15) << 2;
    } else {                               // XX / YY upper triangles
        int t = BT - XY_BLOCKS; g = 0;
        if (t >= TRI_BLOCKS) { t -= TRI_BLOCKS; g = 1; }
        int aa = 0;
        for (;;) { int nb = (67 - aa) >> 2; if (t < nb) break; t -= nb; ++aa; }
        a = aa; b0 = aa + (t << 2);
    }
    const int b = b0 + wid;

    float acc = 0.0f;
    if (g == 2 || b <= 63) {               // dead triangle waves skip
        const float* dA = (g == 1) ? (dInc + 4 * MAT4) : dInc;   // rows
        const float* dB = (g == 0) ? dInc : (dInc + 4 * MAT4);   // cols
        const float weight = (g == 2) ? (-2.0f / 4096.0f)
                                      : ((a == b ? 1.0f : 2.0f) / 4096.0f);

        // per-lane dY rows j=2l, 2l+1 (lane 63's 2nd row masked via c1)
        float ya[16], yb_[16];
        {
            const float* Qb = dB + b * 2048;          // pitch 128*16
            const int j0 = lane << 1;
            const int j1 = (j0 + 1 < 127) ? j0 + 1 : 126;
            const float4* A4 = (const float4*)(Qb + j0 * 16);
            const float4* B4 = (const float4*)(Qb + j1 * 16);
#pragma unroll
            for (int q = 0; q < 4; ++q) {
                float4 va = A4[q], vb = B4[q];
                ya[4*q+0]=va.x;  ya[4*q+1]=va.y;  ya[4*q+2]=va.z;  ya[4*q+3]=va.w;
                yb_[4*q+0]=vb.x; yb_[4*q+1]=vb.y; yb_[4*q+2]=vb.z; yb_[4*q+3]=vb.w;
            }
        }
        // Pin fragments into VGPRs (opaque: cannot be re-sunk into the loop)
#pragma unroll
        for (int d = 0; d < 16; ++d)
            asm volatile("" : "+v"(ya[d]), "+v"(yb_[d]));

        // block-uniform dX base -> s_load rows into SGPR float4 quads
        const int abase = __builtin_amdgcn_readfirstlane(a * 2048);
        const float4* Ar = (const float4*)(dA + abase);

        // depth-4 ring: rows r..r+3 resident in 16 named float4 (SGPRs)
        float4 A0,A1,A2,A3, B0,B1,B2,B3, C0,C1,C2,C3, D0,D1,D2,D3;
        A0=Ar[ 0]; A1=Ar[ 1]; A2=Ar[ 2]; A3=Ar[ 3];
        B0=Ar[ 4]; B1=Ar[ 5]; B2=Ar[ 6]; B3=Ar[ 7];
        C0=Ar[ 8]; C1=Ar[ 9]; C2=Ar[10]; C3=Ar[11];
        D0=Ar[12]; D1=Ar[13]; D2=Ar[14]; D3=Ar[15];

        float g_lo = 1.0f, g_hi = 1.0f;    // G[r][2l+1], G[r][2l+2]
        const bool last = (lane == 63);

        // dual 16-dots read float4 components directly (no unpack movs)
#define SIG_ROW(q0,q1,q2,q3)                                                \
        {                                                                   \
            float s0=-0.5f, s1=-0.5f, t0=-0.5f, t1=-0.5f;                   \
            s0=fmaf(q0.x,ya[ 0],s0); s1=fmaf(q0.y,ya[ 1],s1);               \
            t0=fmaf(q0.x,yb_[ 0],t0); t1=fmaf(q0.y,yb_[ 1],t1);             \
            s0=fmaf(q0.z,ya[ 2],s0); s1=fmaf(q0.w,ya[ 3],s1);               \
            t0=fmaf(q0.z,yb_[ 2],t0); t1=fmaf(q0.w,yb_[ 3],t1);             \
            s0=fmaf(q1.x,ya[ 4],s0); s1=fmaf(q1.y,ya[ 5],s1);               \
            t0=fmaf(q1.x,yb_[ 4],t0); t1=fmaf(q1.y,yb_[ 5],t1);             \
            s0=fmaf(q1.z,ya[ 6],s0); s1=fmaf(q1.w,ya[ 7],s1);               \
            t0=fmaf(q1.z,yb_[ 6],t0); t1=fmaf(q1.w,yb_[ 7],t1);             \
            s0=fmaf(q2.x,ya[ 8],s0); s1=fmaf(q2.y,ya[ 9],s1);               \
            t0=fmaf(q2.x,yb_[ 8],t0); t1=fmaf(q2.y,yb_[ 9],t1);             \
            s0=fmaf(q2.z,ya[10],s0); s1=fmaf(q2.w,ya[11],s1);               \
            t0=fmaf(q2.z,yb_[10],t0); t1=fmaf(q2.w,yb_[11],t1);             \
            s0=fmaf(q3.x,ya[12],s0); s1=fmaf(q3.y,ya[13],s1);               \
            t0=fmaf(q3.x,yb_[12],t0); t1=fmaf(q3.y,yb_[13],t1);             \
            s0=fmaf(q3.z,ya[14],s0); s1=fmaf(q3.w,ya[15],s1);               \
            t0=fmaf(q3.z,yb_[14],t0); t1=fmaf(q3.w,yb_[15],t1);             \
            const float i0 = s0 + s1;          /* inc(r, 2l)   - 1 */       \
            const float i1 = t0 + t1;          /* inc(r, 2l+1) - 1 */       \
            const float gl = wave_shr1(g_hi, 1.0f);  /* G[r][2l] */         \
            const float c0 = fmaf(gl, i0, g_lo);                            \
            const float c1 = last ? 0.0f : fmaf(g_lo, i1, g_hi);            \
            const float S  = wave_scan_incl(c0 + c1);                       \
            const float T  = S + 1.0f;                                      \
            g_lo = T - c1;                                                  \
            g_hi = T;                                                       \
        }

        // rows 0..123: unroll-4, reload each buffer 4 SIG_ROWs before reuse
#pragma unroll 1
        for (int r = 0; r < 124; r += 4) {
            SIG_ROW(A0,A1,A2,A3)
            A0=Ar[4*(r+4)+0]; A1=Ar[4*(r+4)+1]; A2=Ar[4*(r+4)+2]; A3=Ar[4*(r+4)+3];
            SIG_ROW(B0,B1,B2,B3)
            B0=Ar[4*(r+5)+0]; B1=Ar[4*(r+5)+1]; B2=Ar[4*(r+5)+2]; B3=Ar[4*(r+5)+3];
            SIG_ROW(C0,C1,C2,C3)
            C0=Ar[4*(r+6)+0]; C1=Ar[4*(r+6)+1]; C2=Ar[4*(r+6)+2]; C3=Ar[4*(r+6)+3];
            SIG_ROW(D0,D1,D2,D3)
            D0=Ar[4*(r+7)+0]; D1=Ar[4*(r+7)+1]; D2=Ar[4*(r+7)+2]; D3=Ar[4*(r+7)+3];
        }
        // rows 124,125,126 (last iter loaded rows 124..127; 127 = pad)
        SIG_ROW(A0,A1,A2,A3)
        SIG_ROW(B0,B1,B2,B3)
        SIG_ROW(C0,C1,C2,C3)
#undef SIG_ROW

        const float kab = __builtin_bit_cast(float,
            __builtin_amdgcn_readlane(__builtin_bit_cast(int, g_lo), 63));
        acc = weight * kab;
    }

    // fused reduction: 4 waves -> LDS -> one atomic per block
    if (lane == 0) red[wid] = acc;
    __syncthreads();
    if (threadIdx.x == 0)
        atomicAdd(out, (red[0] + red[1]) + (red[2] + red[3]));
}

__global__ __launch_bounds__(256) void sig_reduce2(
    const float* __restrict__ v, float* __restrict__ out, int n)
{
    __shared__ float red[256];
    float s = 0.0f;
    for (int i = threadIdx.x; i < n; i += 256) s += v[i];
    red[threadIdx.x] = s;
    __syncthreads();
    for (int st = 128; st > 0; st >>= 1) {
        if (threadIdx.x < st) red[threadIdx.x] += red[threadIdx.x + st];
        __syncthreads();
    }
    if (threadIdx.x == 0) out[0] = red[0];
}

// ---- fallback (ws too small for increment staging): round-1 kernel ----
__global__ __launch_bounds__(64) void sig_pde_kernel(
    const float* __restrict__ X, const float* __restrict__ Y,
    float* __restrict__ ws)
{
    __shared__ float Xs[2048];
    const int T = blockIdx.x;
    const int g = T >> 12;
    const int t = T & 4095;
    const int a = t >> 6, b = t & 63;
    const int lane = threadIdx.x;
    if (g < 2 && a > b) { if (lane == 0) ws[T] = 0.0f; return; }
    const float* P = (g == 1) ? Y : X;
    const float* Q = (g == 0) ? X : Y;
    const float weight = (g == 2) ? (-2.0f / 4096.0f)
                                  : ((a == b ? 1.0f : 2.0f) / 4096.0f);
    {
        const float4* Pa = (const float4*)(P + a * 2048);
        float4* Xs4 = (float4*)Xs;
#pragma unroll
        for (int k = 0; k < 8; ++k) Xs4[lane + (k << 6)] = Pa[lane + (k << 6)];
    }
    __syncthreads();
    {
        float tmp[32];
#pragma unroll
        for (int k = 0; k < 32; ++k) {
            int idx = lane + (k << 6);
            tmp[k] = (idx < 2032) ? (Xs[idx + 16] - Xs[idx]) : 0.0f;
        }
        __syncthreads();
#pragma unroll
        for (int k = 0; k < 32; ++k) {
            int idx = lane + (k << 6);
            if (idx < 2032) Xs[idx] = tmp[k];
        }
    }
    __syncthreads();
    float y0[16], y1[16];
    {
        const float* Qb = Q + b * 2048;
        const int r0 = lane << 1;
        const int r2 = (r0 + 2 > 127) ? 127 : (r0 + 2);
        const float4* A4 = (const float4*)(Qb + r0 * 16);
        const float4* B4 = (const float4*)(Qb + (r0 + 1) * 16);
        const float4* C4 = (const float4*)(Qb + r2 * 16);
#pragma unroll
        for (int q = 0; q < 4; ++q) {
            float4 ra = A4[q], rb = B4[q], rc = C4[q];
            y0[4*q+0] = rb.x - ra.x;  y1[4*q+0] = rc.x - rb.x;
            y0[4*q+1] = rb.y - ra.y;  y1[4*q+1] = rc.y - rb.y;
            y0[4*q+2] = rb.z - ra.z;  y1[4*q+2] = rc.z - rb.z;
            y0[4*q+3] = rb.w - ra.w;  y1[4*q+3] = rc.w - rb.w;
        }
    }
    float g_lo = 1.0f, g_hi = 1.0f;
    const bool last = (lane == 63);
    for (int r = 0; r < 127; ++r) {
        const float* xrow = Xs + r * 16;
        float s0 = -0.5f, s1 = -0.5f, t0 = -0.5f, t1 = -0.5f;
#pragma unroll
        for (int d = 0; d < 16; d += 2) {
            s0 = fmaf(xrow[d], y0[d], s0);   s1 = fmaf(xrow[d+1], y0[d+1], s1);
            t0 = fmaf(xrow[d], y1[d], t0);   t1 = fmaf(xrow[d+1], y1[d+1], t1);
        }
        const float i0 = s0 + s1, i1 = t0 + t1;
        const float gl = wave_shr1(g_hi, 1.0f);
        const float c0 = fmaf(gl, i0, g_lo);
        const float c1 = last ? 0.0f : fmaf(g_lo, i1, g_hi);
        const float S = wave_scan_incl(c0 + c1);
        g_lo = (S - c1) + 1.0f;
        g_hi = S + 1.0f;
    }
    const float kab = __builtin_bit_cast(float,
        __builtin_amdgcn_readlane(__builtin_bit_cast(int, g_lo), 63));
    if (lane == 0) ws[T] = weight * kab;
}

extern "C" void kernel_launch(void* const* d_in, const int* in_sizes, int n_in,
                              void* d_out, int out_size, void* d_ws, size_t ws_size,
                              hipStream_t stream) {
    const float* X = (const float*)d_in[0];
    const float* Y = (const float*)d_in[1];
    float* out = (float*)d_out;
    float* ws  = (float*)d_ws;

    if (ws_size >= (size_t)2 * MAT4 * sizeof(float4)) {   // 1 MiB staging
        sig_diff<<<254, 256, 0, stream>>>(X, Y, ws, out);
        sig_pde7<<<NBT, 256, 0, stream>>>(ws, out);
    } else {
        sig_pde_kernel<<<12288, 64, 0, stream>>>(X, Y, ws);
        sig_reduce2<<<1, 256, 0, stream>>>(ws, out, 12288);
    }
}

// Round 7
// 134.464 us; speedup vs baseline: 9.7399x; 9.7399x over previous
//
#include <hip/hip_runtime.h>

// Signature-kernel MMD via Goursat PDE — round 8.
// Round-7 postmortem: the named-float4 "SGPR ring" did NOT scalarize
// (SGPR_Count 32) -> 64 ring floats + 32 pinned floats in VGPRs at cap 64
// -> 2.9GB spill, 1300us. Session pattern: every pin/ring variant regressed
// (99.5/100/233/1300 us); only round-2's compiler-chosen schedule (VGPR=28,
// ya/yb re-loaded from L1 each row) hits 93.6us. The reload is the
// compiler's OPTIMAL strategy, not a bug: L1-hit VMEM is cheap, low
// pressure buys occupancy. Stop fighting the allocator.
// Remaining theory for r2's 32% non-issue gap: per-row dX fetch through the
// SCALAR cache (s_load ~200cy from L2, depth-1 prefetch ~150cy ahead) plus
// 16 copy movs/row.
// Round-8 = round-2 verbatim EXCEPT:
//  (1) dX path (block-uniform, 8KB) staged to LDS once per block; per-row
//      4x broadcast ds_read_b128 (uniform addr = conflict-free) replaces
//      the s_load stream and the xr/xn copy loop entirely.
//  (2) fused per-block atomicAdd reduction (proven r4-r6).
// No pins. No named rings. No v2f. 2112 blocks (proven best grid).

#define XY_BLOCKS 1024
#define TRI_BLOCKS 544
#define NBT (XY_BLOCKS + 2 * TRI_BLOCKS)        // 2112 blocks
#define DINC_PER 130048                         // 64*127*16 floats

template <int C, int RM, int BM, bool BC>
__device__ __forceinline__ float dpp0(float x) {
    return __builtin_bit_cast(float, __builtin_amdgcn_update_dpp(
        0, __builtin_bit_cast(int, x), C, RM, BM, BC));
}

// 64-lane inclusive prefix sum, pure VALU (6 dependent adds).
__device__ __forceinline__ float wave_scan_incl(float v) {
    v += dpp0<0x111, 0xf, 0xf, true>(v);   // row_shr:1
    v += dpp0<0x112, 0xf, 0xf, true>(v);   // row_shr:2
    v += dpp0<0x114, 0xf, 0xf, true>(v);   // row_shr:4
    v += dpp0<0x118, 0xf, 0xf, true>(v);   // row_shr:8
    v += dpp0<0x142, 0xa, 0xf, false>(v);  // row_bcast:15 -> rows 1,3
    v += dpp0<0x143, 0xc, 0xf, false>(v);  // row_bcast:31 -> rows 2,3
    return v;
}

// lane l gets lane l-1's x; lane 0 gets `oldv`.
__device__ __forceinline__ float wave_shr1(float x, float oldv) {
    return __builtin_bit_cast(float, __builtin_amdgcn_update_dpp(
        __builtin_bit_cast(int, oldv), __builtin_bit_cast(int, x),
        0x138, 0xf, 0xf, false));          // wave_shr:1
}

// ---- kernel 1: path increments X,Y -> ws (dX at 0, dY at DINC_PER) ----
// (round-2 version, pitch 2032 per path) + zeroes out[0] for fused reduce.
__global__ __launch_bounds__(256) void sig_diff(
    const float* __restrict__ X, const float* __restrict__ Y,
    float* __restrict__ dInc, float* __restrict__ out)
{
    if (blockIdx.x == 0 && threadIdx.x == 0) out[0] = 0.0f;
    int i = blockIdx.x * 256 + threadIdx.x;   // float4 id, 65024 total
    if (i >= 65024) return;
    int which = (i >= 32512) ? 1 : 0;
    int j = i - which * 32512;
    int a = j / 508;                          // 127*4 float4 per path
    int rq = j - a * 508;                     // r*4 + q
    const float* S = which ? Y : X;
    const float4* p = (const float4*)(S + a * 2048) + rq;
    float4 v0 = p[0], v1 = p[4];              // +16 floats = next row
    float4 d;
    d.x = v1.x - v0.x; d.y = v1.y - v0.y;
    d.z = v1.z - v0.z; d.w = v1.w - v0.w;
    ((float4*)dInc)[i] = d;
}

// ---- kernel 2: PDE. 2112 blocks * 4 waves, one (g,a,b0) per block. ----
__global__ __launch_bounds__(256, 8) void sig_pde8(
    const float* __restrict__ dInc, float* __restrict__ out)
{
    __shared__ float4 Xs4[508];            // dX path of row-index a (8128 B)
    __shared__ float red[4];
    const int wid  = threadIdx.x >> 6;
    const int lane = threadIdx.x & 63;
    const int BT   = blockIdx.x;

    // block-uniform decode -> (gram g, a, b0); b = b0 + wave id
    int g, a, b0;
    if (BT < XY_BLOCKS) {                  // XY: dense 64x64
        g = 2; a = BT >> 4; b0 = (BT & 15) << 2;
    } else {                               // XX / YY upper triangles
        int t = BT - XY_BLOCKS; g = 0;
        if (t >= TRI_BLOCKS) { t -= TRI_BLOCKS; g = 1; }
        int aa = 0;
        for (;;) { int nb = (67 - aa) >> 2; if (t < nb) break; t -= nb; ++aa; }
        a = aa; b0 = aa + (t << 2);
    }
    const int b = b0 + wid;

    const float* dA = (g == 1) ? (dInc + DINC_PER) : dInc;   // row paths
    const float* dB = (g == 0) ? dInc : (dInc + DINC_PER);   // col paths

    // stage the block-uniform dX path into LDS (all 256 threads, then sync)
    {
        const float4* Ap = (const float4*)(dA + a * 2032);   // 508 float4
        const int tid = threadIdx.x;
        Xs4[tid] = Ap[tid];
        if (tid + 256 < 508) Xs4[tid + 256] = Ap[tid + 256];
    }
    __syncthreads();

    float acc = 0.0f;
    if (g == 2 || b <= 63) {               // dead triangle waves skip compute
        const float weight = (g == 2) ? (-2.0f / 4096.0f)
                                      : ((a == b ? 1.0f : 2.0f) / 4096.0f);

        // per-lane dY rows j=2l, 2l+1 (lane 63's 2nd row masked via c1).
        // NOT pinned: the compiler re-loads these from L1 inside the loop
        // at its discretion — measured optimal (r2: VGPR=28, 93.6us).
        float ya[16], yb_[16];
        {
            const float* Qb = dB + b * 2032;
            const int j0 = lane << 1;
            const int j1 = (j0 + 1 < 127) ? j0 + 1 : 126;
            const float4* A4 = (const float4*)(Qb + j0 * 16);
            const float4* B4 = (const float4*)(Qb + j1 * 16);
#pragma unroll
            for (int q = 0; q < 4; ++q) {
                float4 va = A4[q], vb = B4[q];
                ya[4*q+0]=va.x;  ya[4*q+1]=va.y;  ya[4*q+2]=va.z;  ya[4*q+3]=va.w;
                yb_[4*q+0]=vb.x; yb_[4*q+1]=vb.y; yb_[4*q+2]=vb.z; yb_[4*q+3]=vb.w;
            }
        }

        float g_lo = 1.0f, g_hi = 1.0f;    // G[r][2l+1], G[r][2l+2]
        const bool last = (lane == 63);

#pragma unroll 1
        for (int r = 0; r < 127; ++r) {
            // broadcast row read: 4x ds_read_b128, uniform address
            float xr[16];
#pragma unroll
            for (int q = 0; q < 4; ++q) {
                float4 v = Xs4[4*r + q];
                xr[4*q+0]=v.x; xr[4*q+1]=v.y; xr[4*q+2]=v.z; xr[4*q+3]=v.w;
            }
            // inc - 1 via accumulators seeded with -0.5 each (2 chains/dot)
            float s0 = -0.5f, s1 = -0.5f, t0 = -0.5f, t1 = -0.5f;
#pragma unroll
            for (int d = 0; d < 16; d += 2) {
                s0 = fmaf(xr[d], ya[d], s0);    s1 = fmaf(xr[d+1], ya[d+1], s1);
                t0 = fmaf(xr[d], yb_[d], t0);   t1 = fmaf(xr[d+1], yb_[d+1], t1);
            }
            const float i0 = s0 + s1;          // inc(r, 2l)   - 1
            const float i1 = t0 + t1;          // inc(r, 2l+1) - 1

            const float gl = wave_shr1(g_hi, 1.0f);     // G[r][2l], lane0->1
            const float c0 = fmaf(gl, i0, g_lo);
            const float c1 = last ? 0.0f : fmaf(g_lo, i1, g_hi);
            const float S = wave_scan_incl(c0 + c1);
            g_lo = (S - c1) + 1.0f;
            g_hi = S + 1.0f;
        }

        const float kab = __builtin_bit_cast(float,
            __builtin_amdgcn_readlane(__builtin_bit_cast(int, g_lo), 63));
        acc = weight * kab;
    }

    // fused reduction: 4 waves -> LDS -> one atomic per block
    if (lane == 0) red[wid] = acc;
    __syncthreads();
    if (threadIdx.x == 0)
        atomicAdd(out, (red[0] + red[1]) + (red[2] + red[3]));
}

__global__ __launch_bounds__(256) void sig_reduce2(
    const float* __restrict__ v, float* __restrict__ out, int n)
{
    __shared__ float red[256];
    float s = 0.0f;
    for (int i = threadIdx.x; i < n; i += 256) s += v[i];
    red[threadIdx.x] = s;
    __syncthreads();
    for (int st = 128; st > 0; st >>= 1) {
        if (threadIdx.x < st) red[threadIdx.x] += red[threadIdx.x + st];
        __syncthreads();
    }
    if (threadIdx.x == 0) out[0] = red[0];
}

// ---- fallback (ws too small for increment staging): round-1 kernel ----
__global__ __launch_bounds__(64) void sig_pde_kernel(
    const float* __restrict__ X, const float* __restrict__ Y,
    float* __restrict__ ws)
{
    __shared__ float Xs[2048];
    const int T = blockIdx.x;
    const int g = T >> 12;
    const int t = T & 4095;
    const int a = t >> 6, b = t & 63;
    const int lane = threadIdx.x;
    if (g < 2 && a > b) { if (lane == 0) ws[T] = 0.0f; return; }
    const float* P = (g == 1) ? Y : X;
    const float* Q = (g == 0) ? X : Y;
    const float weight = (g == 2) ? (-2.0f / 4096.0f)
                                  : ((a == b ? 1.0f : 2.0f) / 4096.0f);
    {
        const float4* Pa = (const float4*)(P + a * 2048);
        float4* Xs4 = (float4*)Xs;
#pragma unroll
        for (int k = 0; k < 8; ++k) Xs4[lane + (k << 6)] = Pa[lane + (k << 6)];
    }
    __syncthreads();
    {
        float tmp[32];
#pragma unroll
        for (int k = 0; k < 32; ++k) {
            int idx = lane + (k << 6);
            tmp[k] = (idx < 2032) ? (Xs[idx + 16] - Xs[idx]) : 0.0f;
        }
        __syncthreads();
#pragma unroll
        for (int k = 0; k < 32; ++k) {
            int idx = lane + (k << 6);
            if (idx < 2032) Xs[idx] = tmp[k];
        }
    }
    __syncthreads();
    float y0[16], y1[16];
    {
        const float* Qb = Q + b * 2048;
        const int r0 = lane << 1;
        const int r2 = (r0 + 2 > 127) ? 127 : (r0 + 2);
        const float4* A4 = (const float4*)(Qb + r0 * 16);
        const float4* B4 = (const float4*)(Qb + (r0 + 1) * 16);
        const float4* C4 = (const float4*)(Qb + r2 * 16);
#pragma unroll
        for (int q = 0; q < 4; ++q) {
            float4 ra = A4[q], rb = B4[q], rc = C4[q];
            y0[4*q+0] = rb.x - ra.x;  y1[4*q+0] = rc.x - rb.x;
            y0[4*q+1] = rb.y - ra.y;  y1[4*q+1] = rc.y - rb.y;
            y0[4*q+2] = rb.z - ra.z;  y1[4*q+2] = rc.z - rb.z;
            y0[4*q+3] = rb.w - ra.w;  y1[4*q+3] = rc.w - rb.w;
        }
    }
    float g_lo = 1.0f, g_hi = 1.0f;
    const bool last = (lane == 63);
    for (int r = 0; r < 127; ++r) {
        const float* xrow = Xs + r * 16;
        float s0 = -0.5f, s1 = -0.5f, t0 = -0.5f, t1 = -0.5f;
#pragma unroll
        for (int d = 0; d < 16; d += 2) {
            s0 = fmaf(xrow[d], y0[d], s0);   s1 = fmaf(xrow[d+1], y0[d+1], s1);
            t0 = fmaf(xrow[d], y1[d], t0);   t1 = fmaf(xrow[d+1], y1[d+1], t1);
        }
        const float i0 = s0 + s1, i1 = t0 + t1;
        const float gl = wave_shr1(g_hi, 1.0f);
        const float c0 = fmaf(gl, i0, g_lo);
        const float c1 = last ? 0.0f : fmaf(g_lo, i1, g_hi);
        const float S = wave_scan_incl(c0 + c1);
        g_lo = (S - c1) + 1.0f;
        g_hi = S + 1.0f;
    }
    const float kab = __builtin_bit_cast(float,
        __builtin_amdgcn_readlane(__builtin_bit_cast(int, g_lo), 63));
    if (lane == 0) ws[T] = weight * kab;
}

extern "C" void kernel_launch(void* const* d_in, const int* in_sizes, int n_in,
                              void* d_out, int out_size, void* d_ws, size_t ws_size,
                              hipStream_t stream) {
    const float* X = (const float*)d_in[0];
    const float* Y = (const float*)d_in[1];
    float* out = (float*)d_out;
    float* ws  = (float*)d_ws;

    const size_t need = (size_t)(2 * DINC_PER) * sizeof(float);
    if (ws_size >= need) {
        sig_diff<<<254, 256, 0, stream>>>(X, Y, ws, out);
        sig_pde8<<<NBT, 256, 0, stream>>>(ws, out);
    } else {
        sig_pde_kernel<<<12288, 64, 0, stream>>>(X, Y, ws);
        sig_reduce2<<<1, 256, 0, stream>>>(ws, out, 12288);
    }
}